// Round 1
// baseline (1879.557 us; speedup 1.0000x reference)
//
#include <hip/hip_runtime.h>

#define T_DIM 512
#define N_DIM 1024
#define K_DIM 2048
#define B_DIM 64

// ---------------------------------------------------------------------------
// Kernel 1: z[b][t][n] = sum_i x[b][i][t] * w[n][i]   (z stored [B][T][N] in d_out)
// fp32 SGEMM, 128x128 tile, BK=8, 256 threads, 8x8 per thread.
// ---------------------------------------------------------------------------
__global__ __launch_bounds__(256) void gemm_z(const float* __restrict__ x,
                                              const float* __restrict__ w,
                                              float* __restrict__ z) {
  const int b  = blockIdx.y;
  const int bt = blockIdx.x & 3;   // T tile (4 x 128)
  const int bn = blockIdx.x >> 2;  // N tile (8 x 128)
  const int t0 = bt * 128, n0 = bn * 128;
  const float* xb = x + (size_t)b * K_DIM * T_DIM;

  __shared__ float As[8][128];  // As[ki][tt] = x[b][k0+ki][t0+tt]
  __shared__ float Bs[8][128];  // Bs[ki][nn] = w[n0+nn][k0+ki]

  const int tid = threadIdx.x;
  const int tx = tid & 15;   // n direction
  const int ty = tid >> 4;   // t direction

  float acc[8][8];
#pragma unroll
  for (int i = 0; i < 8; ++i)
#pragma unroll
    for (int j = 0; j < 8; ++j) acc[i][j] = 0.f;

  const int aki = tid >> 5;          // 0..7
  const int att = (tid & 31) << 2;   // 0..124
  const int bnn = tid >> 1;          // 0..127
  const int bki = (tid & 1) << 2;    // 0 or 4

  const float* xp = xb + (size_t)aki * T_DIM + t0 + att;
  const float* wp = w + (size_t)(n0 + bnn) * K_DIM + bki;

  for (int k0 = 0; k0 < K_DIM; k0 += 8) {
    const float4 av = *reinterpret_cast<const float4*>(xp + (size_t)k0 * T_DIM);
    const float4 bv = *reinterpret_cast<const float4*>(wp + k0);
    *reinterpret_cast<float4*>(&As[aki][att]) = av;
    Bs[bki + 0][bnn] = bv.x;
    Bs[bki + 1][bnn] = bv.y;
    Bs[bki + 2][bnn] = bv.z;
    Bs[bki + 3][bnn] = bv.w;
    __syncthreads();
#pragma unroll
    for (int ki = 0; ki < 8; ++ki) {
      float a[8], bb[8];
#pragma unroll
      for (int j = 0; j < 8; ++j) a[j] = As[ki][ty * 8 + j];
#pragma unroll
      for (int j = 0; j < 8; ++j) bb[j] = Bs[ki][tx * 8 + j];
#pragma unroll
      for (int i = 0; i < 8; ++i)
#pragma unroll
        for (int j = 0; j < 8; ++j) acc[i][j] = fmaf(a[i], bb[j], acc[i][j]);
    }
    __syncthreads();
  }

  float* zb = z + (size_t)b * T_DIM * N_DIM;
#pragma unroll
  for (int i = 0; i < 8; ++i) {
    const int t = t0 + ty * 8 + i;
    float* o = zb + (size_t)t * N_DIM + n0 + tx * 8;
    *reinterpret_cast<float4*>(o)     = make_float4(acc[i][0], acc[i][1], acc[i][2], acc[i][3]);
    *reinterpret_cast<float4*>(o + 4) = make_float4(acc[i][4], acc[i][5], acc[i][6], acc[i][7]);
  }
}

// ---------------------------------------------------------------------------
// Kernel 2: sequential CUBA-KWTA recurrence. One block per batch.
// 256 threads, 4 neurons each. Spikes packed to bits: bits[b][w][n] (w=t/32).
// ---------------------------------------------------------------------------
__global__ __launch_bounds__(256) void kwta_scan(const float* __restrict__ z,
                                                 const float* __restrict__ se,
                                                 unsigned int* __restrict__ bits) {
  const int b = blockIdx.x;
  const int tid = threadIdx.x;
  const int lane = tid & 63;
  const int wid = tid >> 6;

  float a = se[0];
  a = fminf(fmaxf(a, 0.f), 1.f);
  const float ap1 = 1.f + a;
  const float RB = 0.8046875f;  // TH*(N-2K)/N/WS exactly

  __shared__ float part[2][4];

  const float* zb = z + (size_t)b * T_DIM * N_DIM + tid * 4;
  unsigned int* gb = bits + (size_t)b * 16 * N_DIM + tid * 4;

  // prefetch ring, depth 4 (named regs so indexing stays static)
  float4 zq0 = *reinterpret_cast<const float4*>(zb);
  float4 zq1 = *reinterpret_cast<const float4*>(zb + N_DIM);
  float4 zq2 = *reinterpret_cast<const float4*>(zb + 2 * N_DIM);
  float4 zq3 = *reinterpret_cast<const float4*>(zb + 3 * N_DIM);

  float u0 = 0.f, u1 = 0.f, u2 = 0.f, u3 = 0.f;
  float v0 = 0.f, v1 = 0.f, v2 = 0.f, v3 = 0.f;
  float s0 = 0.f, s1 = 0.f, s2 = 0.f, s3 = 0.f;
  float S = 0.f;  // sum of previous spikes (exact integer)
  unsigned int c0 = 0, c1 = 0, c2 = 0, c3 = 0;

#define NEURON(U, V, SV, C, ZV)                         \
  {                                                     \
    const float fb  = fmaf(ap1, SV, -S) + RB;           \
    const float inp = ZV + fb;                          \
    U = fmaf(0.75f, U, inp);                            \
    V = fmaf(0.9f, V, U);                               \
    const bool sp = (V >= 1.0f);                        \
    SV = sp ? 1.0f : 0.0f;                              \
    V  = sp ? 0.0f : V;                                 \
    C |= ((unsigned int)sp) << (t & 31);                \
  }

#define STEP(KK, ZQ)                                                    \
  {                                                                     \
    const int t = tb + KK;                                              \
    const float4 z4 = ZQ;                                               \
    const int tn = (t + 4 < T_DIM) ? (t + 4) : (T_DIM - 1);             \
    ZQ = *reinterpret_cast<const float4*>(zb + (size_t)tn * N_DIM);     \
    NEURON(u0, v0, s0, c0, z4.x);                                       \
    NEURON(u1, v1, s1, c1, z4.y);                                       \
    NEURON(u2, v2, s2, c2, z4.z);                                       \
    NEURON(u3, v3, s3, c3, z4.w);                                       \
    float loc = (s0 + s1) + (s2 + s3);                                  \
    loc += __shfl_xor(loc, 1);                                          \
    loc += __shfl_xor(loc, 2);                                          \
    loc += __shfl_xor(loc, 4);                                          \
    loc += __shfl_xor(loc, 8);                                          \
    loc += __shfl_xor(loc, 16);                                         \
    loc += __shfl_xor(loc, 32);                                         \
    if (lane == 0) part[KK & 1][wid] = loc;                             \
    __syncthreads();                                                    \
    S = (part[KK & 1][0] + part[KK & 1][1]) +                           \
        (part[KK & 1][2] + part[KK & 1][3]);                            \
    if ((t & 31) == 31) {                                               \
      const int wd = t >> 5;                                            \
      *reinterpret_cast<uint4*>(gb + (size_t)wd * N_DIM) =              \
          make_uint4(c0, c1, c2, c3);                                   \
      c0 = c1 = c2 = c3 = 0;                                            \
    }                                                                   \
  }

  for (int tb = 0; tb < T_DIM; tb += 4) {
    STEP(0, zq0)
    STEP(1, zq1)
    STEP(2, zq2)
    STEP(3, zq3)
  }
#undef STEP
#undef NEURON
}

// ---------------------------------------------------------------------------
// Kernel 3: expand bits -> out[b][n][t] fp32 with 1-step delay shift.
// out[b][n][0] = 0 ; out[b][n][t] = spike[t-1]. Coalesced 32B/lane writes.
// ---------------------------------------------------------------------------
__global__ __launch_bounds__(256) void expand_out(const unsigned int* __restrict__ bits,
                                                  float* __restrict__ out) {
  const int gid = blockIdx.x * 256 + threadIdx.x;  // 64*1024*64 total
  const int l = gid & 63;                          // covers 8 timesteps
  const int row = gid >> 6;                        // b*1024 + n
  const int b = row >> 10;
  const int n = row & 1023;
  const unsigned int* r = bits + (size_t)b * 16 * N_DIM + n;

  unsigned int byte;
  if (l == 0) {
    byte = (r[0] << 1) & 0xFFu;  // t=0 -> 0, t=1..7 -> spikes 0..6
  } else {
    const int src = 8 * l - 1;
    const int w0 = src >> 5;
    const unsigned int lo = r[(size_t)w0 * N_DIM];
    const unsigned int hi = (w0 < 15) ? r[(size_t)(w0 + 1) * N_DIM] : 0u;
    const unsigned long long comb = ((unsigned long long)hi << 32) | (unsigned long long)lo;
    byte = (unsigned int)(comb >> (src & 31)) & 0xFFu;
  }

  float f[8];
#pragma unroll
  for (int k = 0; k < 8; ++k) f[k] = (float)((byte >> k) & 1u);

  float* o = out + ((size_t)row << 9) + (l << 3);
  *reinterpret_cast<float4*>(o)     = make_float4(f[0], f[1], f[2], f[3]);
  *reinterpret_cast<float4*>(o + 4) = make_float4(f[4], f[5], f[6], f[7]);
}

// ---------------------------------------------------------------------------
extern "C" void kernel_launch(void* const* d_in, const int* in_sizes, int n_in,
                              void* d_out, int out_size, void* d_ws, size_t ws_size,
                              hipStream_t stream) {
  const float* x  = (const float*)d_in[0];   // [64][2048][512]
  const float* w  = (const float*)d_in[1];   // [1024][2048]
  const float* se = (const float*)d_in[2];   // [1]
  float* out = (float*)d_out;                // [64][1024][512] fp32
  unsigned int* bits = (unsigned int*)d_ws;  // [64][16][1024] u32 = 4 MB

  // Phase 1: z (layout [B][T][N]) materialized INTO d_out (same size as out).
  gemm_z<<<dim3(32, 64), 256, 0, stream>>>(x, w, out);
  // Phase 2: sequential scan, consumes z from d_out, emits spike bits to d_ws.
  kwta_scan<<<64, 256, 0, stream>>>(out, se, bits);
  // Phase 3: expand bits into d_out (overwrites z, which is dead by now).
  expand_out<<<16384, 256, 0, stream>>>(bits, out);
}

// Round 2
// 757.587 us; speedup vs baseline: 2.4810x; 2.4810x over previous
//
#include <hip/hip_runtime.h>

#define T_DIM 512
#define N_DIM 1024
#define K_DIM 2048
#define B_DIM 64

typedef _Float16 f16;
typedef _Float16 f16x4 __attribute__((ext_vector_type(4)));
typedef _Float16 f16x8 __attribute__((ext_vector_type(8)));
typedef float f32x16 __attribute__((ext_vector_type(16)));

// ---------------------------------------------------------------------------
// Kernel 1: z[b][t][n] = sum_i w[n][i] * x[b][i][t]   (z into d_out, [B][T][N])
// f16x2 split emulation on matrix cores:
//   w' = 64*w = w0 + w1*2^-12 ;  x = x0 + x1*2^-12   (f16 components)
//   acc0 += w0*x0 ; acc1 += w0*x1 + w1*x0            (w1*x1 ~ 2^-24, dropped)
//   z = acc0/64 + acc1/(64*4096)
// 128x128 tile, BK=32, 4 waves of 64x64, mfma_f32_32x32x16_f16.
// LDS tiles [row][comp][k] with 128B rows, XOR-swizzled ((row&7)<<4 bytes).
// ---------------------------------------------------------------------------
__global__ __launch_bounds__(256, 2) void gemm_split(const float* __restrict__ x,
                                                     const float* __restrict__ w,
                                                     float* __restrict__ z) {
  const int b = blockIdx.y;
  const int bn = blockIdx.x >> 2;
  const int bt = blockIdx.x & 3;
  const int n0 = bn * 128, t0 = bt * 128;
  const float* xb = x + (size_t)b * K_DIM * T_DIM;

  __shared__ f16 sA[128 * 64];  // [m][comp][k32], swizzled
  __shared__ f16 sB[128 * 64];  // [t][comp][k32], swizzled

  const int tid = threadIdx.x;
  const int lane = tid & 63;
  const int l31 = lane & 31;
  const int lhi = lane >> 5;
  const int wv = tid >> 6;      // wave 0..3
  const int wm = wv >> 1, wt = wv & 1;

  // A staging: m = (tid>>3) + 32p, float4 at k = 4*(tid&7)
  const int amr = tid >> 3;
  const int aj = tid & 7;
  const float* pA = w + (size_t)(n0 + amr) * K_DIM + aj * 4;
  // B staging: t = tid&127, k-half = tid>>7, 16 scalar loads along k
  const int btt = tid & 127;
  const int bkh = tid >> 7;
  const float* pB = xb + (size_t)(bkh * 16) * T_DIM + t0 + btt;

  // fragment-read offsets: e = row*64 + ((((c<<2)|(kc<<1)|lhi) ^ (l31&7)) << 3)
  const int swz7 = l31 & 7;
  int kOff[2][2];
#pragma unroll
  for (int c = 0; c < 2; ++c)
#pragma unroll
    for (int kc = 0; kc < 2; ++kc)
      kOff[c][kc] = ((((c << 2) | (kc << 1) | lhi) ^ swz7) << 3);
  const int rowA0 = (wm * 64 + l31) * 64;
  const int rowB0 = (wt * 64 + l31) * 64;

  f32x16 acc0[2][2], acc1[2][2];
#pragma unroll
  for (int i = 0; i < 2; ++i)
#pragma unroll
    for (int j = 0; j < 2; ++j)
#pragma unroll
      for (int r = 0; r < 16; ++r) {
        acc0[i][j][r] = 0.f;
        acc1[i][j][r] = 0.f;
      }

  float4 ra[4];
  float rb[16];
#pragma unroll
  for (int p = 0; p < 4; ++p)
    ra[p] = *(const float4*)(pA + (size_t)(32 * p) * K_DIM);
#pragma unroll
  for (int jj = 0; jj < 16; ++jj) rb[jj] = pB[(size_t)jj * T_DIM];

  for (int it = 0; it < 64; ++it) {
    // ---- write phase: split held registers into f16 comps -> LDS ----
#pragma unroll
    for (int p = 0; p < 4; ++p) {
      const int m = amr + 32 * p;
      const int base = m * 64;
      const int sw = (m & 7) << 3;
      float vv[4] = {ra[p].x, ra[p].y, ra[p].z, ra[p].w};
      f16x4 h0, h1;
#pragma unroll
      for (int q = 0; q < 4; ++q) {
        const float v = vv[q] * 64.f;
        const f16 a = (f16)v;
        const float r = (v - (float)a) * 4096.f;
        h0[q] = a;
        h1[q] = (f16)r;
      }
      *(f16x4*)&sA[base + ((aj * 4) ^ sw)] = h0;
      *(f16x4*)&sA[base + ((32 + aj * 4) ^ sw)] = h1;
    }
    {
      const int base = btt * 64;
      const int sw = (btt & 7) << 3;
      f16x8 h0[2], h1[2];
#pragma unroll
      for (int s = 0; s < 2; ++s)
#pragma unroll
        for (int q = 0; q < 8; ++q) {
          const float v = rb[s * 8 + q];
          const f16 a = (f16)v;
          const float r = (v - (float)a) * 4096.f;
          h0[s][q] = a;
          h1[s][q] = (f16)r;
        }
#pragma unroll
      for (int s = 0; s < 2; ++s) {
        *(f16x8*)&sB[base + ((bkh * 16 + 8 * s) ^ sw)] = h0[s];
        *(f16x8*)&sB[base + ((32 + bkh * 16 + 8 * s) ^ sw)] = h1[s];
      }
    }
    __syncthreads();

    // ---- prefetch next K-tile into registers (latency hides under MFMA) ----
    if (it < 63) {
      const int k0n = (it + 1) * 32;
#pragma unroll
      for (int p = 0; p < 4; ++p)
        ra[p] = *(const float4*)(pA + (size_t)(32 * p) * K_DIM + k0n);
#pragma unroll
      for (int jj = 0; jj < 16; ++jj)
        rb[jj] = pB[(size_t)(k0n + jj) * T_DIM];
    }

    // ---- compute phase ----
#pragma unroll
    for (int kc = 0; kc < 2; ++kc) {
      f16x8 A0[2], A1[2], B0[2], B1[2];
#pragma unroll
      for (int f = 0; f < 2; ++f) {
        A0[f] = *(const f16x8*)&sA[rowA0 + f * 32 * 64 + kOff[0][kc]];
        A1[f] = *(const f16x8*)&sA[rowA0 + f * 32 * 64 + kOff[1][kc]];
        B0[f] = *(const f16x8*)&sB[rowB0 + f * 32 * 64 + kOff[0][kc]];
        B1[f] = *(const f16x8*)&sB[rowB0 + f * 32 * 64 + kOff[1][kc]];
      }
#pragma unroll
      for (int f = 0; f < 2; ++f)
#pragma unroll
        for (int g = 0; g < 2; ++g) {
          acc0[f][g] = __builtin_amdgcn_mfma_f32_32x32x16_f16(A0[f], B0[g], acc0[f][g], 0, 0, 0);
          acc1[f][g] = __builtin_amdgcn_mfma_f32_32x32x16_f16(A0[f], B1[g], acc1[f][g], 0, 0, 0);
          acc1[f][g] = __builtin_amdgcn_mfma_f32_32x32x16_f16(A1[f], B0[g], acc1[f][g], 0, 0, 0);
        }
    }
    __syncthreads();
  }

  // ---- epilogue: combine scales, store z[t][n] ----
  float* zb = z + (size_t)b * T_DIM * N_DIM;
  const float C0 = 0.015625f;           // 1/64
  const float C1 = 3.814697265625e-06f; // 1/(64*4096)
#pragma unroll
  for (int f = 0; f < 2; ++f)
#pragma unroll
    for (int g = 0; g < 2; ++g) {
      const int tt = t0 + wt * 64 + g * 32 + l31;
      float* orow = zb + (size_t)tt * N_DIM + n0 + wm * 64 + f * 32 + lhi * 4;
#pragma unroll
      for (int q = 0; q < 4; ++q) {
        float4 o;
        o.x = acc0[f][g][4 * q + 0] * C0 + acc1[f][g][4 * q + 0] * C1;
        o.y = acc0[f][g][4 * q + 1] * C0 + acc1[f][g][4 * q + 1] * C1;
        o.z = acc0[f][g][4 * q + 2] * C0 + acc1[f][g][4 * q + 2] * C1;
        o.w = acc0[f][g][4 * q + 3] * C0 + acc1[f][g][4 * q + 3] * C1;
        *(float4*)(orow + q * 8) = o;
      }
    }
}

// ---------------------------------------------------------------------------
// Kernel 2: sequential CUBA-KWTA recurrence. One block per batch.
// ---------------------------------------------------------------------------
__global__ __launch_bounds__(256) void kwta_scan(const float* __restrict__ z,
                                                 const float* __restrict__ se,
                                                 unsigned int* __restrict__ bits) {
  const int b = blockIdx.x;
  const int tid = threadIdx.x;
  const int lane = tid & 63;
  const int wid = tid >> 6;

  float a = se[0];
  a = fminf(fmaxf(a, 0.f), 1.f);
  const float ap1 = 1.f + a;
  const float RB = 0.8046875f;

  __shared__ float part[2][4];

  const float* zb = z + (size_t)b * T_DIM * N_DIM + tid * 4;
  unsigned int* gb = bits + (size_t)b * 16 * N_DIM + tid * 4;

  float4 zq0 = *reinterpret_cast<const float4*>(zb);
  float4 zq1 = *reinterpret_cast<const float4*>(zb + N_DIM);
  float4 zq2 = *reinterpret_cast<const float4*>(zb + 2 * N_DIM);
  float4 zq3 = *reinterpret_cast<const float4*>(zb + 3 * N_DIM);

  float u0 = 0.f, u1 = 0.f, u2 = 0.f, u3 = 0.f;
  float v0 = 0.f, v1 = 0.f, v2 = 0.f, v3 = 0.f;
  float s0 = 0.f, s1 = 0.f, s2 = 0.f, s3 = 0.f;
  float S = 0.f;
  unsigned int c0 = 0, c1 = 0, c2 = 0, c3 = 0;

#define NEURON(U, V, SV, C, ZV)                         \
  {                                                     \
    const float fb  = fmaf(ap1, SV, -S) + RB;           \
    const float inp = ZV + fb;                          \
    U = fmaf(0.75f, U, inp);                            \
    V = fmaf(0.9f, V, U);                               \
    const bool sp = (V >= 1.0f);                        \
    SV = sp ? 1.0f : 0.0f;                              \
    V  = sp ? 0.0f : V;                                 \
    C |= ((unsigned int)sp) << (t & 31);                \
  }

#define STEP(KK, ZQ)                                                    \
  {                                                                     \
    const int t = tb + KK;                                              \
    const float4 z4 = ZQ;                                               \
    const int tn = (t + 4 < T_DIM) ? (t + 4) : (T_DIM - 1);             \
    ZQ = *reinterpret_cast<const float4*>(zb + (size_t)tn * N_DIM);     \
    NEURON(u0, v0, s0, c0, z4.x);                                       \
    NEURON(u1, v1, s1, c1, z4.y);                                       \
    NEURON(u2, v2, s2, c2, z4.z);                                       \
    NEURON(u3, v3, s3, c3, z4.w);                                       \
    float loc = (s0 + s1) + (s2 + s3);                                  \
    loc += __shfl_xor(loc, 1);                                          \
    loc += __shfl_xor(loc, 2);                                          \
    loc += __shfl_xor(loc, 4);                                          \
    loc += __shfl_xor(loc, 8);                                          \
    loc += __shfl_xor(loc, 16);                                         \
    loc += __shfl_xor(loc, 32);                                         \
    if (lane == 0) part[KK & 1][wid] = loc;                             \
    __syncthreads();                                                    \
    S = (part[KK & 1][0] + part[KK & 1][1]) +                           \
        (part[KK & 1][2] + part[KK & 1][3]);                            \
    if ((t & 31) == 31) {                                               \
      const int wd = t >> 5;                                            \
      *reinterpret_cast<uint4*>(gb + (size_t)wd * N_DIM) =              \
          make_uint4(c0, c1, c2, c3);                                   \
      c0 = c1 = c2 = c3 = 0;                                            \
    }                                                                   \
  }

  for (int tb = 0; tb < T_DIM; tb += 4) {
    STEP(0, zq0)
    STEP(1, zq1)
    STEP(2, zq2)
    STEP(3, zq3)
  }
#undef STEP
#undef NEURON
}

// ---------------------------------------------------------------------------
// Kernel 3: expand bits -> out[b][n][t] fp32 with 1-step delay shift.
// ---------------------------------------------------------------------------
__global__ __launch_bounds__(256) void expand_out(const unsigned int* __restrict__ bits,
                                                  float* __restrict__ out) {
  const int gid = blockIdx.x * 256 + threadIdx.x;
  const int l = gid & 63;
  const int row = gid >> 6;
  const int b = row >> 10;
  const int n = row & 1023;
  const unsigned int* r = bits + (size_t)b * 16 * N_DIM + n;

  unsigned int byte;
  if (l == 0) {
    byte = (r[0] << 1) & 0xFFu;
  } else {
    const int src = 8 * l - 1;
    const int w0 = src >> 5;
    const unsigned int lo = r[(size_t)w0 * N_DIM];
    const unsigned int hi = (w0 < 15) ? r[(size_t)(w0 + 1) * N_DIM] : 0u;
    const unsigned long long comb = ((unsigned long long)hi << 32) | (unsigned long long)lo;
    byte = (unsigned int)(comb >> (src & 31)) & 0xFFu;
  }

  float f[8];
#pragma unroll
  for (int k = 0; k < 8; ++k) f[k] = (float)((byte >> k) & 1u);

  float* o = out + ((size_t)row << 9) + (l << 3);
  *reinterpret_cast<float4*>(o)     = make_float4(f[0], f[1], f[2], f[3]);
  *reinterpret_cast<float4*>(o + 4) = make_float4(f[4], f[5], f[6], f[7]);
}

// ---------------------------------------------------------------------------
extern "C" void kernel_launch(void* const* d_in, const int* in_sizes, int n_in,
                              void* d_out, int out_size, void* d_ws, size_t ws_size,
                              hipStream_t stream) {
  const float* x  = (const float*)d_in[0];   // [64][2048][512]
  const float* w  = (const float*)d_in[1];   // [1024][2048]
  const float* se = (const float*)d_in[2];   // [1]
  float* out = (float*)d_out;                // [64][1024][512] fp32
  unsigned int* bits = (unsigned int*)d_ws;  // [64][16][1024] u32 = 4 MB

  gemm_split<<<dim3(32, 64), 256, 0, stream>>>(x, w, out);
  kwta_scan<<<64, 256, 0, stream>>>(out, se, bits);
  expand_out<<<16384, 256, 0, stream>>>(bits, out);
}